// Round 1
// baseline (68.387 us; speedup 1.0000x reference)
//
#include <hip/hip_runtime.h>

#define RNK 32
#define VOC 32000
#define BSZ 512
#define SEQ 24

// ---------------------------------------------------------------------------
// Kernel A: m[r][s] = sum_v core[r][v][s]   (core is (R, V, R) row-major)
// 131 MB compulsory read -> HBM-bound. 32 r-slabs x 125 chunks = 4000 blocks.
// Each thread: 8 float4 loads; phase (s mod 32) is loop-invariant because the
// per-iteration stride (256 threads * 4 floats) is a multiple of 32.
// ---------------------------------------------------------------------------
__global__ __launch_bounds__(256) void reduce_m_kernel(const float* __restrict__ core,
                                                       float* __restrict__ gm) {
    const int r     = blockIdx.x & 31;
    const int chunk = blockIdx.x >> 5;          // 0..124
    const int tid   = threadIdx.x;

    const float4* slab = (const float4*)(core + (size_t)r * VOC * RNK);
    const int base = chunk * 2048 + tid;        // float4 index

    float a0 = 0.f, a1 = 0.f, a2 = 0.f, a3 = 0.f;
    #pragma unroll
    for (int i = 0; i < 8; ++i) {
        float4 v = slab[base + i * 256];
        a0 += v.x; a1 += v.y; a2 += v.z; a3 += v.w;
    }

    __shared__ float ml[RNK];
    if (tid < RNK) ml[tid] = 0.f;
    __syncthreads();

    const int s0 = (tid & 7) * 4;               // (tid*4) % 32
    atomicAdd(&ml[s0 + 0], a0);
    atomicAdd(&ml[s0 + 1], a1);
    atomicAdd(&ml[s0 + 2], a2);
    atomicAdd(&ml[s0 + 3], a3);
    __syncthreads();

    if (tid < RNK) atomicAdd(&gm[r * RNK + tid], ml[tid]);
}

// ---------------------------------------------------------------------------
// Kernel B: p_tilde[b] = alpha @ (prod_t M_{y[b,t]}) @ beta
// 2 rows per 64-lane wave: lane = half*32 + s holds state[s] of its row.
// matvec: new[s] = sum_r shfl(state, half*32+r) * M[r][s]; M column for lane s
// is 32 coalesced-across-lanes loads (128 B segments). Next token's matrix is
// prefetched into registers to hide load latency behind the fma chain.
// ---------------------------------------------------------------------------
__global__ __launch_bounds__(256) void chain_kernel(const float* __restrict__ core,
                                                    const int* __restrict__ y,
                                                    const float* __restrict__ alpha,
                                                    const float* __restrict__ beta,
                                                    float* __restrict__ out) {
    const int lane   = threadIdx.x & 63;
    const int s      = lane & 31;
    const int base32 = lane & 32;               // 0 or 32: this row's lane group
    const int row    = blockIdx.x * 8 + (threadIdx.x >> 5);
    const size_t strideR = (size_t)VOC * RNK;   // stride between r-rows of one token matrix

    float state = alpha[s];

    // prefetch matrix for t=0
    float cur[RNK];
    {
        const int tok = y[row * SEQ + 0];
        const float* mb = core + (size_t)tok * RNK + s;
        #pragma unroll
        for (int r = 0; r < RNK; ++r) cur[r] = mb[(size_t)r * strideR];
    }

    for (int t = 0; t < SEQ; ++t) {
        float nxt[RNK];
        if (t + 1 < SEQ) {
            const int tok2 = y[row * SEQ + t + 1];
            const float* mb2 = core + (size_t)tok2 * RNK + s;
            #pragma unroll
            for (int r = 0; r < RNK; ++r) nxt[r] = mb2[(size_t)r * strideR];
        }

        // 4-way split accumulator to shorten the fma dependency chain
        float acc0 = 0.f, acc1 = 0.f, acc2 = 0.f, acc3 = 0.f;
        #pragma unroll
        for (int r = 0; r < RNK; r += 4) {
            acc0 = fmaf(__shfl(state, base32 + r + 0, 64), cur[r + 0], acc0);
            acc1 = fmaf(__shfl(state, base32 + r + 1, 64), cur[r + 1], acc1);
            acc2 = fmaf(__shfl(state, base32 + r + 2, 64), cur[r + 2], acc2);
            acc3 = fmaf(__shfl(state, base32 + r + 3, 64), cur[r + 3], acc3);
        }
        state = (acc0 + acc1) + (acc2 + acc3);

        #pragma unroll
        for (int r = 0; r < RNK; ++r) cur[r] = nxt[r];
    }

    float p = state * beta[s];
    #pragma unroll
    for (int m = 16; m >= 1; m >>= 1) p += __shfl_xor(p, m, 64);  // masks <32: stays in half
    if (s == 0) out[row] = p;
}

// ---------------------------------------------------------------------------
// Kernel C: z = (alpha @ m^T_chain ... ) -- 24 matvecs with m, then dot beta, *BSZ
// ---------------------------------------------------------------------------
__global__ void zchain_kernel(const float* __restrict__ gm,
                              const float* __restrict__ alpha,
                              const float* __restrict__ beta,
                              float* __restrict__ out) {
    const int lane   = threadIdx.x & 63;
    const int s      = lane & 31;
    const int base32 = lane & 32;

    float v = alpha[s];
    for (int t = 0; t < SEQ; ++t) {
        float acc = 0.f;
        #pragma unroll
        for (int r = 0; r < RNK; ++r)
            acc = fmaf(__shfl(v, base32 + r, 64), gm[r * RNK + s], acc);
        v = acc;
    }
    float z = v * beta[s];
    #pragma unroll
    for (int m = 16; m >= 1; m >>= 1) z += __shfl_xor(z, m, 64);
    if (threadIdx.x == 0) out[BSZ] = z * (float)BSZ;
}

extern "C" void kernel_launch(void* const* d_in, const int* in_sizes, int n_in,
                              void* d_out, int out_size, void* d_ws, size_t ws_size,
                              hipStream_t stream) {
    const int*   y     = (const int*)d_in[0];
    const float* alpha = (const float*)d_in[1];
    const float* beta  = (const float*)d_in[2];
    const float* core  = (const float*)d_in[3];
    float* out = (float*)d_out;
    float* gm  = (float*)d_ws;                  // 1024 floats of scratch

    hipMemsetAsync(gm, 0, RNK * RNK * sizeof(float), stream);
    reduce_m_kernel<<<32 * 125, 256, 0, stream>>>(core, gm);
    chain_kernel<<<BSZ / 8, 256, 0, stream>>>(core, y, alpha, beta, out);
    zchain_kernel<<<1, 64, 0, stream>>>(gm, alpha, beta, out);
}

// Round 2
// 45.291 us; speedup vs baseline: 1.5099x; 1.5099x over previous
//
#include <hip/hip_runtime.h>

#define RNK 32
#define VOC 32000
#define BSZ 512
#define SEQ 24

#define CHAIN_BLOCKS 128          // 4 rows/block (1 row per 64-lane wave)
#define REDUCE_BLOCKS 4000        // 32 r-slabs x 125 chunks

// ---------------------------------------------------------------------------
// Fused kernel. Blocks [0, CHAIN_BLOCKS) run the selected-token chain
// (latency-bound, dispatched first so they're resident for the whole kernel);
// blocks [CHAIN_BLOCKS, CHAIN_BLOCKS+REDUCE_BLOCKS) stream core to build
// gm[r][s] = sum_v core[r][v][s] (HBM-bound). The two roles overlap.
// ---------------------------------------------------------------------------
__global__ __launch_bounds__(256) void fused_kernel(const float* __restrict__ core,
                                                    const int* __restrict__ y,
                                                    const float* __restrict__ alpha,
                                                    const float* __restrict__ beta,
                                                    float* __restrict__ out,
                                                    float* __restrict__ gm) {
    if (blockIdx.x < CHAIN_BLOCKS) {
        // ---------------- chain role: p_tilde[row] ----------------
        const int tid  = threadIdx.x;
        const int lane = tid & 63;
        const int s    = lane & 31;
        const int half = lane >> 5;           // 0: rows 0..15, 1: rows 16..31
        const int row  = blockIdx.x * 4 + (tid >> 6);
        const size_t strideR = (size_t)VOC * RNK;     // r-row stride in core
        const size_t halfOff = (size_t)half * 16 * strideR;

        // whole token row in one coalesced load, broadcast later via shfl
        int ytok = (lane < SEQ) ? y[row * SEQ + lane] : 0;

        float state = alpha[s];               // replicated in both halves

        float buf[3][16];                     // 2-deep prefetch pipeline
        {
            const int tok = __shfl(ytok, 0, 64);
            const float* mb = core + (size_t)tok * RNK + s + halfOff;
            #pragma unroll
            for (int i = 0; i < 16; ++i) buf[0][i] = mb[(size_t)i * strideR];
        }
        {
            const int tok = __shfl(ytok, 1, 64);
            const float* mb = core + (size_t)tok * RNK + s + halfOff;
            #pragma unroll
            for (int i = 0; i < 16; ++i) buf[1][i] = mb[(size_t)i * strideR];
        }

        #pragma unroll
        for (int t = 0; t < SEQ; ++t) {       // full unroll -> static buf indices
            if (t + 2 < SEQ) {
                const int tok = __shfl(ytok, t + 2, 64);
                const float* mb = core + (size_t)tok * RNK + s + halfOff;
                #pragma unroll
                for (int i = 0; i < 16; ++i) buf[(t + 2) % 3][i] = mb[(size_t)i * strideR];
            }
            // partial dot over this half's 16 rows; 4-way split accumulator
            float a0 = 0.f, a1 = 0.f, a2 = 0.f, a3 = 0.f;
            #pragma unroll
            for (int i = 0; i < 16; i += 4) {
                a0 = fmaf(__shfl(state, half * 16 + i + 0, 64), buf[t % 3][i + 0], a0);
                a1 = fmaf(__shfl(state, half * 16 + i + 1, 64), buf[t % 3][i + 1], a1);
                a2 = fmaf(__shfl(state, half * 16 + i + 2, 64), buf[t % 3][i + 2], a2);
                a3 = fmaf(__shfl(state, half * 16 + i + 3, 64), buf[t % 3][i + 3], a3);
            }
            const float acc = (a0 + a1) + (a2 + a3);
            state = acc + __shfl_xor(acc, 32, 64);   // combine halves, re-replicate
        }

        float p = state * beta[s];
        #pragma unroll
        for (int m = 16; m >= 1; m >>= 1) p += __shfl_xor(p, m, 64); // within-half sum
        if (lane == 0) out[row] = p;
    } else {
        // ---------------- reduce role: gm[r][s] += sum_v core[r][v][s] ----------------
        const int bid   = blockIdx.x - CHAIN_BLOCKS;
        const int r     = bid & 31;
        const int chunk = bid >> 5;           // 0..124
        const int tid   = threadIdx.x;

        const float4* slab = (const float4*)(core + (size_t)r * VOC * RNK);
        const int base = chunk * 2048 + tid;  // float4 index

        float a0 = 0.f, a1 = 0.f, a2 = 0.f, a3 = 0.f;
        #pragma unroll
        for (int i = 0; i < 8; ++i) {
            float4 v = slab[base + i * 256];
            a0 += v.x; a1 += v.y; a2 += v.z; a3 += v.w;
        }

        __shared__ float ml[RNK];
        if (tid < RNK) ml[tid] = 0.f;
        __syncthreads();

        const int s0 = (tid & 7) * 4;         // (tid*4) % 32, loop-invariant phase
        atomicAdd(&ml[s0 + 0], a0);
        atomicAdd(&ml[s0 + 1], a1);
        atomicAdd(&ml[s0 + 2], a2);
        atomicAdd(&ml[s0 + 3], a3);
        __syncthreads();

        if (tid < RNK) atomicAdd(&gm[r * RNK + tid], ml[tid]);
    }
}

// ---------------------------------------------------------------------------
// z = alpha @ m^SEQ @ beta * BSZ  (single wave; runs after fused kernel)
// ---------------------------------------------------------------------------
__global__ void zchain_kernel(const float* __restrict__ gm,
                              const float* __restrict__ alpha,
                              const float* __restrict__ beta,
                              float* __restrict__ out) {
    const int lane = threadIdx.x & 63;
    const int s    = lane & 31;
    const int half = lane >> 5;

    float col[16];                            // this lane's half-column of m
    #pragma unroll
    for (int i = 0; i < 16; ++i) col[i] = gm[(half * 16 + i) * RNK + s];

    float v = alpha[s];
    for (int t = 0; t < SEQ; ++t) {
        float a0 = 0.f, a1 = 0.f, a2 = 0.f, a3 = 0.f;
        #pragma unroll
        for (int i = 0; i < 16; i += 4) {
            a0 = fmaf(__shfl(v, half * 16 + i + 0, 64), col[i + 0], a0);
            a1 = fmaf(__shfl(v, half * 16 + i + 1, 64), col[i + 1], a1);
            a2 = fmaf(__shfl(v, half * 16 + i + 2, 64), col[i + 2], a2);
            a3 = fmaf(__shfl(v, half * 16 + i + 3, 64), col[i + 3], a3);
        }
        const float acc = (a0 + a1) + (a2 + a3);
        v = acc + __shfl_xor(acc, 32, 64);
    }
    float z = v * beta[s];
    #pragma unroll
    for (int m = 16; m >= 1; m >>= 1) z += __shfl_xor(z, m, 64);
    if (lane == 0) out[BSZ] = z * (float)BSZ;
}

extern "C" void kernel_launch(void* const* d_in, const int* in_sizes, int n_in,
                              void* d_out, int out_size, void* d_ws, size_t ws_size,
                              hipStream_t stream) {
    const int*   y     = (const int*)d_in[0];
    const float* alpha = (const float*)d_in[1];
    const float* beta  = (const float*)d_in[2];
    const float* core  = (const float*)d_in[3];
    float* out = (float*)d_out;
    float* gm  = (float*)d_ws;                // 1024 floats of scratch

    hipMemsetAsync(gm, 0, RNK * RNK * sizeof(float), stream);
    fused_kernel<<<CHAIN_BLOCKS + REDUCE_BLOCKS, 256, 0, stream>>>(core, y, alpha, beta, out, gm);
    zchain_kernel<<<1, 64, 0, stream>>>(gm, alpha, beta, out);
}